// Round 7
// baseline (220.765 us; speedup 1.0000x reference)
//
#include <hip/hip_runtime.h>

// Sinkhorn, B=8 N=1024 C=64, T=2, eps=0.1, 20 iters, scale=1e-3.
// Only batch 7 contributes (reference returns losses[-1]).
// u = 1/(K v), v = 1/(K^T u), 20 rounds; loss = sum u_i K_ij v_j W_ij,
// W_ij = -0.1*log(K_ij).
//
// ROUND 7: keep the LL-sync loop structure (proven, 2.8us/exchange); attack
// the two remaining cost centers:
//  - buildK was LDS-scalar-read bound (512 ds_read_b32/thread/tile): now
//    f32x4 staging, sy row register-blocked (the 4 q-outputs of a thread
//    share jl -> load sy row ONCE into 16 f32x4 regs), sx read as f32x4
//    broadcast. Accumulation order unchanged (c ascending, one accumulator)
//    -> bitwise-identical K.
//  - loop: publish u/v straight from lane 0 registers right after each wsum
//    (no LDS stage[] bounce, no pre-publish __syncthreads); sv double-buffered
//    (svA=v-data, svB=u-data) so one __syncthreads per half-round suffices.
//  LL mechanics, tags, generations, dot order, loss: bit-identical to the
//  passing round-6 kernel.

static constexpr int N = 1024;
static constexpr int C = 64;

// Workspace layout (floats).
static constexpr int WS_XS  = 0;          // softmax(y_s[7]/2) : 1024*64
static constexpr int WS_YS  = 65536;      // softmax(y_t[7]/2) : 1024*64
static constexpr int WS_K   = 131072;     // K   : 1024*1024
static constexpr int WS_KT  = 1179648;    // K^T : 1024*1024
static constexpr int WS_ULL = 2228224;    // u LL units: 1024 x {f32,tag} = 2048 f
static constexpr int WS_VLL = 2230272;    // v LL units: 2048 f
static constexpr int WS_PLL = 2232320;    // partial LL units: 256 x {f32,tag}

typedef float    f32x4 __attribute__((ext_vector_type(4)));
typedef unsigned u32x4 __attribute__((ext_vector_type(4)));
typedef unsigned u32x2 __attribute__((ext_vector_type(2)));

__device__ __forceinline__ float wsum(float v) {
    #pragma unroll
    for (int o = 32; o > 0; o >>= 1) v += __shfl_down(v, o, 64);
    return v;
}
__device__ __forceinline__ float wmax(float v) {
    #pragma unroll
    for (int o = 32; o > 0; o >>= 1) v = fmaxf(v, __shfl_down(v, o, 64));
    return v;
}

// Publish one LL unit {val, g}: single 8B store, sc0 sc1 -> lands at the LLC.
__device__ __forceinline__ void ll_write(float* unit, float val, unsigned g) {
    u32x2 d;
    d.x = __float_as_uint(val);
    d.y = g;
    asm volatile("global_store_dwordx2 %0, %1, off sc0 sc1"
                 :: "v"(unit), "v"(d) : "memory");
}

// Poll-read 4 LL units (thread t covers units t*4..t*4+3) into sv[t*4..].
// Two 16B sc0 sc1 loads per try; accept when all 4 embedded tags == g.
// 8B-atomic stores guarantee each {val,tag} pair is internally consistent.
__device__ __forceinline__ void ll_read4(const float* buf, unsigned g,
                                         float* sv, int t) {
    const float* p = buf + t * 8;          // 4 units * 2 floats
    u32x4 a, b;
    for (;;) {
        asm volatile(
            "global_load_dwordx4 %0, %2, off sc0 sc1\n\t"
            "global_load_dwordx4 %1, %2, off offset:16 sc0 sc1\n\t"
            "s_waitcnt vmcnt(0)"
            : "=&v"(a), "=&v"(b) : "v"(p) : "memory");
        if (a.y == g && a.w == g && b.y == g && b.w == g) break;
        __builtin_amdgcn_s_sleep(1);
    }
    f32x4 vv;
    vv.x = __uint_as_float(a.x);
    vv.y = __uint_as_float(a.z);
    vv.z = __uint_as_float(b.x);
    vv.w = __uint_as_float(b.z);
    *(f32x4*)&sv[t * 4] = vv;
}

// ---- 1: softmax over N axis (dim=1), batch 7. One block per column; 128 blocks.
__global__ void __launch_bounds__(256)
softmax_k(const float* __restrict__ ysrc, const float* __restrict__ ytrc,
          float* __restrict__ ws)
{
    __shared__ float sm[4];
    const int tid = threadIdx.x, bid = blockIdx.x;
    const int wid = tid >> 6, lane = tid & 63;
    const float* src = ((bid < C) ? ysrc : ytrc) + 7 * N * C;
    float* dst = ws + ((bid < C) ? WS_XS : WS_YS);
    const int c = bid & (C - 1);

    float vals[4];
    float m = -1e30f;
    #pragma unroll
    for (int q = 0; q < 4; ++q) {
        vals[q] = src[(q * 256 + tid) * C + c] * 0.5f;   // y / T, T = 2
        m = fmaxf(m, vals[q]);
    }
    m = wmax(m);
    if (lane == 0) sm[wid] = m;
    __syncthreads();
    m = fmaxf(fmaxf(sm[0], sm[1]), fmaxf(sm[2], sm[3]));
    float s = 0.f;
    #pragma unroll
    for (int q = 0; q < 4; ++q) { vals[q] = expf(vals[q] - m); s += vals[q]; }
    s = wsum(s);
    __syncthreads();                 // protect sm reuse
    if (lane == 0) sm[wid] = s;
    __syncthreads();
    s = sm[0] + sm[1] + sm[2] + sm[3];
    const float inv = 1.0f / s;
    #pragma unroll
    for (int q = 0; q < 4; ++q) dst[(q * 256 + tid) * C + c] = vals[q] * inv;
}

// ---- 2: K_ij = exp(-10 * sum_c |x_ic - y_jc|), plus K^T; 32x32 tiles, 4/block.
//        Vectorized: f32x4 staging; sy row register-blocked (one load serves
//        all 4 q-outputs); sx f32x4 broadcast reads. Accumulation order is
//        exactly the original (c ascending, single accumulator).
//        Blocks 0..3 write the initial v LL units' VALUE slots (1.0f); tags
//        stay 0 from the in-launch memset (= expected tag of generation 0).
__global__ void __launch_bounds__(256)
buildK_k(float* __restrict__ ws)
{
    __shared__ __align__(16) float sx[32 * 64];
    __shared__ __align__(16) float sy[32 * 68];   // stride 68: 16B-aligned rows
    __shared__ float kt[32 * 33];
    float* xs  = ws + WS_XS;
    float* ysm = ws + WS_YS;
    float* K   = ws + WS_K;
    float* KT  = ws + WS_KT;
    const int tid = threadIdx.x, bid = blockIdx.x;
    const int jl = tid & 31;

    if (bid < 4) ws[WS_VLL + (bid * 256 + tid) * 2] = 1.0f;   // v := 1 (LL value)

    #pragma unroll 1
    for (int t = 0; t < 4; ++t) {
        const int tt = bid * 4 + t;
        const int ti = tt >> 5, tj = tt & 31;
        __syncthreads();
        {   // stage x tile (stride 64) and y tile (stride 68), f32x4
            const f32x4* xsrc = (const f32x4*)(xs + ti * 2048);
            f32x4* dx = (f32x4*)sx;
            dx[tid]       = xsrc[tid];
            dx[tid + 256] = xsrc[tid + 256];
            const f32x4* ysrc = (const f32x4*)(ysm + tj * 2048);
            #pragma unroll
            for (int h = 0; h < 2; ++h) {
                const int k4 = tid + h * 256;          // f32x4 index 0..511
                const int row = k4 >> 4, c4 = k4 & 15;
                *(f32x4*)&sy[row * 68 + c4 * 4] = ysrc[k4];
            }
        }
        __syncthreads();
        // Register-load this thread's sy row (shared by all 4 q-outputs).
        f32x4 yr[16];
        #pragma unroll
        for (int c4 = 0; c4 < 16; ++c4)
            yr[c4] = *(const f32x4*)&sy[jl * 68 + c4 * 4];
        float kv[4];
        #pragma unroll
        for (int q = 0; q < 4; ++q) {
            const int il = (q * 256 + tid) >> 5;
            float a = 0.f;
            #pragma unroll
            for (int c4 = 0; c4 < 16; ++c4) {
                const f32x4 xv = *(const f32x4*)&sx[il * 64 + c4 * 4];
                a += fabsf(xv.x - yr[c4].x);        // c = 4*c4 + 0..3,
                a += fabsf(xv.y - yr[c4].y);        // ascending, single acc:
                a += fabsf(xv.z - yr[c4].z);        // identical order to the
                a += fabsf(xv.w - yr[c4].w);        // scalar original
            }
            kv[q] = expf(-10.0f * a);                       // exp(-W/eps)
            K[(ti * 32 + il) * N + tj * 32 + jl] = kv[q];   // coalesced over jl
        }
        __syncthreads();
        #pragma unroll
        for (int q = 0; q < 4; ++q) {
            const int idx = q * 256 + tid;
            kt[(idx >> 5) * 33 + (idx & 31)] = kv[q];
        }
        __syncthreads();
        #pragma unroll
        for (int q = 0; q < 4; ++q) {
            const int idx = q * 256 + tid;
            const int jl2 = idx >> 5, il2 = idx & 31;
            KT[(tj * 32 + jl2) * N + ti * 32 + il2] = kt[il2 * 33 + jl2];
        }
    }
}

// ---- 3: persistent loop kernel. 64 blocks x 256 threads; block owns rows
//         bid*16 .. bid*16+15 of both K and KT, resident in LDS. All cross-
//         block exchange via LL units; publish straight from lane0 registers.
__global__ void __launch_bounds__(256)
sinkhorn_loop_k(float* __restrict__ ws, float* __restrict__ out)
{
    __shared__ __align__(16) float rows[32 * 1024];  // K rows | KT rows (128KB)
    __shared__ __align__(16) float svA[1024];        // staged v
    __shared__ __align__(16) float svB[1024];        // staged u
    __shared__ float fsm[4];
    const int tid = threadIdx.x, bid = blockIdx.x;
    const int wid = tid >> 6, lane = tid & 63;

    // Preload this block's 16 K rows + 16 KT rows (rows are contiguous).
    {
        const f32x4* Ksrc  = (const f32x4*)(ws + WS_K  + bid * 16 * N);
        const f32x4* KTsrc = (const f32x4*)(ws + WS_KT + bid * 16 * N);
        f32x4* dK  = (f32x4*)rows;
        f32x4* dKT = (f32x4*)(rows + 16 * N);
        #pragma unroll 4
        for (int q = 0; q < 16; ++q) dK[tid + 256 * q]  = Ksrc[tid + 256 * q];
        #pragma unroll 4
        for (int q = 0; q < 16; ++q) dKT[tid + 256 * q] = KTsrc[tid + 256 * q];
    }
    __syncthreads();

    float* uLL = ws + WS_ULL;
    float* vLL = ws + WS_VLL;
    float* pLL = ws + WS_PLL;
    const float* rK  = rows + (wid * 4) * N;
    const float* rKT = rows + 16 * N + (wid * 4) * N;
    const int ub = (bid * 16 + wid * 4) * 2;   // this wave's LL unit base (floats)
    float u_s[4];
    unsigned g = 0;          // u-steps publish odd tags, v-steps even

    #pragma unroll 1
    for (int it = 0; it < 20; ++it) {
        // ---- u = 1/(K v): consume v@g into svA, publish u@g+1.
        ll_read4(vLL, g, svA, tid);
        __syncthreads();
        ++g;
        #pragma unroll
        for (int s = 0; s < 4; ++s) {
            const f32x4* Kr = (const f32x4*)(rK + s * N);
            const f32x4 k0 = Kr[lane], k1 = Kr[lane + 64],
                        k2 = Kr[lane + 128], k3 = Kr[lane + 192];
            const f32x4 b0 = *(const f32x4*)&svA[(lane) * 4];
            const f32x4 b1 = *(const f32x4*)&svA[(lane + 64) * 4];
            const f32x4 b2 = *(const f32x4*)&svA[(lane + 128) * 4];
            const f32x4 b3 = *(const f32x4*)&svA[(lane + 192) * 4];
            float acc = 0.f;
            acc += k0.x * b0.x + k0.y * b0.y + k0.z * b0.z + k0.w * b0.w;
            acc += k1.x * b1.x + k1.y * b1.y + k1.z * b1.z + k1.w * b1.w;
            acc += k2.x * b2.x + k2.y * b2.y + k2.z * b2.z + k2.w * b2.w;
            acc += k3.x * b3.x + k3.y * b3.y + k3.z * b3.z + k3.w * b3.w;
            acc = wsum(acc);
            if (lane == 0) {                    // publish immediately
                u_s[s] = 1.0f / acc;
                ll_write(uLL + ub + s * 2, u_s[s], g);
            }
        }

        // ---- v = 1/(K^T u): consume u@g into svB, publish v@g+1.
        ll_read4(uLL, g, svB, tid);
        __syncthreads();
        ++g;
        #pragma unroll
        for (int s = 0; s < 4; ++s) {
            const f32x4* Kr = (const f32x4*)(rKT + s * N);
            const f32x4 k0 = Kr[lane], k1 = Kr[lane + 64],
                        k2 = Kr[lane + 128], k3 = Kr[lane + 192];
            const f32x4 b0 = *(const f32x4*)&svB[(lane) * 4];
            const f32x4 b1 = *(const f32x4*)&svB[(lane + 64) * 4];
            const f32x4 b2 = *(const f32x4*)&svB[(lane + 128) * 4];
            const f32x4 b3 = *(const f32x4*)&svB[(lane + 192) * 4];
            float acc = 0.f;
            acc += k0.x * b0.x + k0.y * b0.y + k0.z * b0.z + k0.w * b0.w;
            acc += k1.x * b1.x + k1.y * b1.y + k1.z * b1.z + k1.w * b1.w;
            acc += k2.x * b2.x + k2.y * b2.y + k2.z * b2.z + k2.w * b2.w;
            acc += k3.x * b3.x + k3.y * b3.y + k3.z * b3.z + k3.w * b3.w;
            acc = wsum(acc);
            if (lane == 0)
                ll_write(vLL + ub + s * 2, 1.0f / acc, g);
        }
    }

    // ---- Loss: consume final v@40; partials as LL units tagged 41.
    ll_read4(vLL, g, svA, tid);          // g == 40
    __syncthreads();
    {
        float p = 0.f;
        #pragma unroll
        for (int s = 0; s < 4; ++s) {
            const float* Kr = rK + s * N;      // LDS copy == K row bits
            float acc = 0.f;
            for (int j = lane; j < N; j += 64) {
                const float kk = Kr[j];
                acc += kk * svA[j] * logf(kk);
            }
            acc = wsum(acc);
            if (lane == 0) p += u_s[s] * acc;
        }
        if (lane == 0) ll_write(pLL + (bid * 4 + wid) * 2, p, 41u);
    }

    // ---- final: block 0 polls the 256 partial units, reduces, writes out.
    if (bid == 0) {
        const float* pp = pLL + tid * 2;
        u32x2 c;
        for (;;) {
            asm volatile("global_load_dwordx2 %0, %1, off sc0 sc1\n\t"
                         "s_waitcnt vmcnt(0)"
                         : "=&v"(c) : "v"(pp) : "memory");
            if (c.y == 41u) break;
            __builtin_amdgcn_s_sleep(1);
        }
        float acc = __uint_as_float(c.x);
        acc = wsum(acc);
        if (lane == 0) fsm[wid] = acc;
        __syncthreads();
        if (tid == 0)
            out[0] = -1e-4f * (fsm[0] + fsm[1] + fsm[2] + fsm[3]);  // 1e-3*(-0.1)
    }
}

extern "C" void kernel_launch(void* const* d_in, const int* in_sizes, int n_in,
                              void* d_out, int out_size, void* d_ws, size_t ws_size,
                              hipStream_t stream) {
    const float* y_s = (const float*)d_in[0];
    const float* y_t = (const float*)d_in[1];
    float* ws = (float*)d_ws;

    // Zero all LL regions (tags live in poisoned workspace); graph-capturable,
    // replayed every launch. 2048+2048+512 floats = 18432 B.
    hipMemsetAsync((char*)d_ws + (size_t)WS_ULL * sizeof(float), 0,
                   (size_t)(2048 + 2048 + 512) * sizeof(float), stream);
    softmax_k<<<dim3(128), dim3(256), 0, stream>>>(y_s, y_t, ws);
    buildK_k<<<dim3(256), dim3(256), 0, stream>>>(ws);
    sinkhorn_loop_k<<<dim3(64), dim3(256), 0, stream>>>(ws, (float*)d_out);
}

// Round 8
// 192.638 us; speedup vs baseline: 1.1460x; 1.1460x over previous
//
#include <hip/hip_runtime.h>

// Sinkhorn, B=8 N=1024 C=64, T=2, eps=0.1, 20 iters, scale=1e-3.
// Only batch 7 contributes (reference returns losses[-1]).
// u = 1/(K v), v = 1/(K^T u), 20 rounds; loss = sum u_i K_ij v_j W_ij,
// W_ij = -0.1*log(K_ij).
//
// ROUND 8: recombination of the two proven-best pieces:
//  - buildK_k: round-7 vectorized version (f32x4 staging, register-blocked
//    sy row, c-ascending single-accumulator order -> bitwise-identical K).
//    Measured ~19us faster than the scalar version.
//  - sinkhorn_loop_k: round-6 version EXACTLY (LL data-embedded sync with
//    BATCHED publish: each block's 16 units = one 128B LLC line written in
//    one shot by threads 0..15; measured 115us loop). Round-7's spread-out
//    per-wave publish caused poll retry storms (FETCH +40%, loop +35us) and
//    is reverted.
//  LL mechanics: {f32 value, u32 generation} 8B units, sc0sc1 stores/loads,
//  exact-tag accept, memset-zeroed tags, kernel-boundary coherence for K/KT.

static constexpr int N = 1024;
static constexpr int C = 64;

// Workspace layout (floats).
static constexpr int WS_XS  = 0;          // softmax(y_s[7]/2) : 1024*64
static constexpr int WS_YS  = 65536;      // softmax(y_t[7]/2) : 1024*64
static constexpr int WS_K   = 131072;     // K   : 1024*1024
static constexpr int WS_KT  = 1179648;    // K^T : 1024*1024
static constexpr int WS_ULL = 2228224;    // u LL units: 1024 x {f32,tag} = 2048 f
static constexpr int WS_VLL = 2230272;    // v LL units: 2048 f
static constexpr int WS_PLL = 2232320;    // partial LL units: 256 x {f32,tag}

typedef float    f32x4 __attribute__((ext_vector_type(4)));
typedef unsigned u32x4 __attribute__((ext_vector_type(4)));
typedef unsigned u32x2 __attribute__((ext_vector_type(2)));

__device__ __forceinline__ float wsum(float v) {
    #pragma unroll
    for (int o = 32; o > 0; o >>= 1) v += __shfl_down(v, o, 64);
    return v;
}
__device__ __forceinline__ float wmax(float v) {
    #pragma unroll
    for (int o = 32; o > 0; o >>= 1) v = fmaxf(v, __shfl_down(v, o, 64));
    return v;
}

// Publish one LL unit {val, g}: single 8B store, sc0 sc1 -> lands at the LLC.
__device__ __forceinline__ void ll_write(float* unit, float val, unsigned g) {
    u32x2 d;
    d.x = __float_as_uint(val);
    d.y = g;
    asm volatile("global_store_dwordx2 %0, %1, off sc0 sc1"
                 :: "v"(unit), "v"(d) : "memory");
}

// Poll-read 4 LL units (thread t covers units t*4..t*4+3) into sv[t*4..].
// Two 16B sc0 sc1 loads per try; accept when all 4 embedded tags == g.
// 8B-atomic stores guarantee each {val,tag} pair is internally consistent.
__device__ __forceinline__ void ll_read4(const float* buf, unsigned g,
                                         float* sv, int t) {
    const float* p = buf + t * 8;          // 4 units * 2 floats
    u32x4 a, b;
    for (;;) {
        asm volatile(
            "global_load_dwordx4 %0, %2, off sc0 sc1\n\t"
            "global_load_dwordx4 %1, %2, off offset:16 sc0 sc1\n\t"
            "s_waitcnt vmcnt(0)"
            : "=&v"(a), "=&v"(b) : "v"(p) : "memory");
        if (a.y == g && a.w == g && b.y == g && b.w == g) break;
        __builtin_amdgcn_s_sleep(1);
    }
    const int u0 = t * 4;
    sv[u0 + 0] = __uint_as_float(a.x);
    sv[u0 + 1] = __uint_as_float(a.z);
    sv[u0 + 2] = __uint_as_float(b.x);
    sv[u0 + 3] = __uint_as_float(b.z);
}

// ---- 1: softmax over N axis (dim=1), batch 7. One block per column; 128 blocks.
__global__ void __launch_bounds__(256)
softmax_k(const float* __restrict__ ysrc, const float* __restrict__ ytrc,
          float* __restrict__ ws)
{
    __shared__ float sm[4];
    const int tid = threadIdx.x, bid = blockIdx.x;
    const int wid = tid >> 6, lane = tid & 63;
    const float* src = ((bid < C) ? ysrc : ytrc) + 7 * N * C;
    float* dst = ws + ((bid < C) ? WS_XS : WS_YS);
    const int c = bid & (C - 1);

    float vals[4];
    float m = -1e30f;
    #pragma unroll
    for (int q = 0; q < 4; ++q) {
        vals[q] = src[(q * 256 + tid) * C + c] * 0.5f;   // y / T, T = 2
        m = fmaxf(m, vals[q]);
    }
    m = wmax(m);
    if (lane == 0) sm[wid] = m;
    __syncthreads();
    m = fmaxf(fmaxf(sm[0], sm[1]), fmaxf(sm[2], sm[3]));
    float s = 0.f;
    #pragma unroll
    for (int q = 0; q < 4; ++q) { vals[q] = expf(vals[q] - m); s += vals[q]; }
    s = wsum(s);
    __syncthreads();                 // protect sm reuse
    if (lane == 0) sm[wid] = s;
    __syncthreads();
    s = sm[0] + sm[1] + sm[2] + sm[3];
    const float inv = 1.0f / s;
    #pragma unroll
    for (int q = 0; q < 4; ++q) dst[(q * 256 + tid) * C + c] = vals[q] * inv;
}

// ---- 2: K_ij = exp(-10 * sum_c |x_ic - y_jc|), plus K^T; 32x32 tiles, 4/block.
//        Vectorized (round-7 proven): f32x4 staging; sy row register-blocked
//        (one load serves all 4 q-outputs); sx f32x4 broadcast reads.
//        Accumulation order exactly the scalar original (c ascending, single
//        accumulator) -> bitwise-identical K.
//        Blocks 0..3 write the initial v LL units' VALUE slots (1.0f); tags
//        stay 0 from the in-launch memset (= expected tag of generation 0).
__global__ void __launch_bounds__(256)
buildK_k(float* __restrict__ ws)
{
    __shared__ __align__(16) float sx[32 * 64];
    __shared__ __align__(16) float sy[32 * 68];   // stride 68: 16B-aligned rows
    __shared__ float kt[32 * 33];
    float* xs  = ws + WS_XS;
    float* ysm = ws + WS_YS;
    float* K   = ws + WS_K;
    float* KT  = ws + WS_KT;
    const int tid = threadIdx.x, bid = blockIdx.x;
    const int jl = tid & 31;

    if (bid < 4) ws[WS_VLL + (bid * 256 + tid) * 2] = 1.0f;   // v := 1 (LL value)

    #pragma unroll 1
    for (int t = 0; t < 4; ++t) {
        const int tt = bid * 4 + t;
        const int ti = tt >> 5, tj = tt & 31;
        __syncthreads();
        {   // stage x tile (stride 64) and y tile (stride 68), f32x4
            const f32x4* xsrc = (const f32x4*)(xs + ti * 2048);
            f32x4* dx = (f32x4*)sx;
            dx[tid]       = xsrc[tid];
            dx[tid + 256] = xsrc[tid + 256];
            const f32x4* ysrc = (const f32x4*)(ysm + tj * 2048);
            #pragma unroll
            for (int h = 0; h < 2; ++h) {
                const int k4 = tid + h * 256;          // f32x4 index 0..511
                const int row = k4 >> 4, c4 = k4 & 15;
                *(f32x4*)&sy[row * 68 + c4 * 4] = ysrc[k4];
            }
        }
        __syncthreads();
        // Register-load this thread's sy row (shared by all 4 q-outputs).
        f32x4 yr[16];
        #pragma unroll
        for (int c4 = 0; c4 < 16; ++c4)
            yr[c4] = *(const f32x4*)&sy[jl * 68 + c4 * 4];
        float kv[4];
        #pragma unroll
        for (int q = 0; q < 4; ++q) {
            const int il = (q * 256 + tid) >> 5;
            float a = 0.f;
            #pragma unroll
            for (int c4 = 0; c4 < 16; ++c4) {
                const f32x4 xv = *(const f32x4*)&sx[il * 64 + c4 * 4];
                a += fabsf(xv.x - yr[c4].x);        // c = 4*c4 + 0..3,
                a += fabsf(xv.y - yr[c4].y);        // ascending, single acc:
                a += fabsf(xv.z - yr[c4].z);        // identical order to the
                a += fabsf(xv.w - yr[c4].w);        // scalar original
            }
            kv[q] = expf(-10.0f * a);                       // exp(-W/eps)
            K[(ti * 32 + il) * N + tj * 32 + jl] = kv[q];   // coalesced over jl
        }
        __syncthreads();
        #pragma unroll
        for (int q = 0; q < 4; ++q) {
            const int idx = q * 256 + tid;
            kt[(idx >> 5) * 33 + (idx & 31)] = kv[q];
        }
        __syncthreads();
        #pragma unroll
        for (int q = 0; q < 4; ++q) {
            const int idx = q * 256 + tid;
            const int jl2 = idx >> 5, il2 = idx & 31;
            KT[(tj * 32 + jl2) * N + ti * 32 + il2] = kt[il2 * 33 + jl2];
        }
    }
}

// ---- 3: persistent loop kernel (round-6 EXACT). 64 blocks x 256 threads;
//         block owns rows bid*16..bid*16+15 of K and KT, resident in LDS.
//         Cross-block exchange via LL units; BATCHED publish: each block's 16
//         units = one 128B line, written in one shot by threads 0..15.
__global__ void __launch_bounds__(256)
sinkhorn_loop_k(float* __restrict__ ws, float* __restrict__ out)
{
    __shared__ __align__(16) float rows[32 * 1024];  // K rows | KT rows (128KB)
    __shared__ __align__(16) float sv[1024];
    __shared__ float stage[16];
    __shared__ float fsm[4];
    const int tid = threadIdx.x, bid = blockIdx.x;
    const int wid = tid >> 6, lane = tid & 63;

    // Preload this block's 16 K rows + 16 KT rows (rows are contiguous).
    {
        const f32x4* Ksrc  = (const f32x4*)(ws + WS_K  + bid * 16 * N);
        const f32x4* KTsrc = (const f32x4*)(ws + WS_KT + bid * 16 * N);
        f32x4* dK  = (f32x4*)rows;
        f32x4* dKT = (f32x4*)(rows + 16 * N);
        #pragma unroll 4
        for (int q = 0; q < 16; ++q) dK[tid + 256 * q]  = Ksrc[tid + 256 * q];
        #pragma unroll 4
        for (int q = 0; q < 16; ++q) dKT[tid + 256 * q] = KTsrc[tid + 256 * q];
    }
    __syncthreads();

    float* uLL = ws + WS_ULL;
    float* vLL = ws + WS_VLL;
    float* pLL = ws + WS_PLL;
    const float* rK  = rows + (wid * 4) * N;
    const float* rKT = rows + 16 * N + (wid * 4) * N;
    float u_s[4];
    unsigned g = 0;          // generation: u-steps publish odd, v-steps even

    #pragma unroll 1
    for (int it = 0; it < 20; ++it) {
        // ---- u = 1/(K v): consume v@g, publish u@g+1.
        ll_read4(vLL, g, sv, tid);
        __syncthreads();
        #pragma unroll
        for (int s = 0; s < 4; ++s) {
            const f32x4* Kr = (const f32x4*)(rK + s * N);
            const f32x4 k0 = Kr[lane], k1 = Kr[lane + 64],
                        k2 = Kr[lane + 128], k3 = Kr[lane + 192];
            const f32x4 b0 = *(const f32x4*)&sv[(lane) * 4];
            const f32x4 b1 = *(const f32x4*)&sv[(lane + 64) * 4];
            const f32x4 b2 = *(const f32x4*)&sv[(lane + 128) * 4];
            const f32x4 b3 = *(const f32x4*)&sv[(lane + 192) * 4];
            float acc = 0.f;
            acc += k0.x * b0.x + k0.y * b0.y + k0.z * b0.z + k0.w * b0.w;
            acc += k1.x * b1.x + k1.y * b1.y + k1.z * b1.z + k1.w * b1.w;
            acc += k2.x * b2.x + k2.y * b2.y + k2.z * b2.z + k2.w * b2.w;
            acc += k3.x * b3.x + k3.y * b3.y + k3.z * b3.z + k3.w * b3.w;
            acc = wsum(acc);
            if (lane == 0) { u_s[s] = 1.0f / acc; stage[wid * 4 + s] = u_s[s]; }
        }
        __syncthreads();     // all dots done (sv free), stage complete
        ++g;
        if (tid < 16) ll_write(uLL + (bid * 16 + tid) * 2, stage[tid], g);

        // ---- v = 1/(K^T u): consume u@g, publish v@g+1.
        ll_read4(uLL, g, sv, tid);
        __syncthreads();
        #pragma unroll
        for (int s = 0; s < 4; ++s) {
            const f32x4* Kr = (const f32x4*)(rKT + s * N);
            const f32x4 k0 = Kr[lane], k1 = Kr[lane + 64],
                        k2 = Kr[lane + 128], k3 = Kr[lane + 192];
            const f32x4 b0 = *(const f32x4*)&sv[(lane) * 4];
            const f32x4 b1 = *(const f32x4*)&sv[(lane + 64) * 4];
            const f32x4 b2 = *(const f32x4*)&sv[(lane + 128) * 4];
            const f32x4 b3 = *(const f32x4*)&sv[(lane + 192) * 4];
            float acc = 0.f;
            acc += k0.x * b0.x + k0.y * b0.y + k0.z * b0.z + k0.w * b0.w;
            acc += k1.x * b1.x + k1.y * b1.y + k1.z * b1.z + k1.w * b1.w;
            acc += k2.x * b2.x + k2.y * b2.y + k2.z * b2.z + k2.w * b2.w;
            acc += k3.x * b3.x + k3.y * b3.y + k3.z * b3.z + k3.w * b3.w;
            acc = wsum(acc);
            if (lane == 0) stage[wid * 4 + s] = 1.0f / acc;
        }
        __syncthreads();
        ++g;
        if (tid < 16) ll_write(vLL + (bid * 16 + tid) * 2, stage[tid], g);
    }

    // ---- Loss: consume final v@40; partials as LL units tagged 41.
    ll_read4(vLL, g, sv, tid);           // g == 40
    __syncthreads();
    {
        float p = 0.f;
        #pragma unroll
        for (int s = 0; s < 4; ++s) {
            const float* Kr = rK + s * N;      // LDS copy == K row bits
            float acc = 0.f;
            for (int j = lane; j < N; j += 64) {
                const float kk = Kr[j];
                acc += kk * sv[j] * logf(kk);
            }
            acc = wsum(acc);
            if (lane == 0) p += u_s[s] * acc;
        }
        if (lane == 0) ll_write(pLL + (bid * 4 + wid) * 2, p, 41u);
    }

    // ---- final: block 0 polls the 256 partial units, reduces, writes out.
    if (bid == 0) {
        const float* pp = pLL + tid * 2;
        u32x2 c;
        for (;;) {
            asm volatile("global_load_dwordx2 %0, %1, off sc0 sc1\n\t"
                         "s_waitcnt vmcnt(0)"
                         : "=&v"(c) : "v"(pp) : "memory");
            if (c.y == 41u) break;
            __builtin_amdgcn_s_sleep(1);
        }
        float acc = __uint_as_float(c.x);
        acc = wsum(acc);
        if (lane == 0) fsm[wid] = acc;
        __syncthreads();
        if (tid == 0)
            out[0] = -1e-4f * (fsm[0] + fsm[1] + fsm[2] + fsm[3]);  // 1e-3*(-0.1)
    }
}

extern "C" void kernel_launch(void* const* d_in, const int* in_sizes, int n_in,
                              void* d_out, int out_size, void* d_ws, size_t ws_size,
                              hipStream_t stream) {
    const float* y_s = (const float*)d_in[0];
    const float* y_t = (const float*)d_in[1];
    float* ws = (float*)d_ws;

    // Zero all LL regions (tags live in poisoned workspace); graph-capturable,
    // replayed every launch. 2048+2048+512 floats = 18432 B.
    hipMemsetAsync((char*)d_ws + (size_t)WS_ULL * sizeof(float), 0,
                   (size_t)(2048 + 2048 + 512) * sizeof(float), stream);
    softmax_k<<<dim3(128), dim3(256), 0, stream>>>(y_s, y_t, ws);
    buildK_k<<<dim3(256), dim3(256), 0, stream>>>(ws);
    sinkhorn_loop_k<<<dim3(64), dim3(256), 0, stream>>>(ws, (float*)d_out);
}

// Round 9
// 188.968 us; speedup vs baseline: 1.1683x; 1.0194x over previous
//
#include <hip/hip_runtime.h>

// Sinkhorn, B=8 N=1024 C=64, T=2, eps=0.1, 20 iters, scale=1e-3.
// Only batch 7 contributes (reference returns losses[-1]).
// u = 1/(K v), v = 1/(K^T u), 20 rounds; loss = sum u_i K_ij v_j W_ij,
// W_ij = -0.1*log(K_ij).
//
// ROUND 9: round-8 config (proven: loop 115us, vectorized buildK) with the
// memset dispatch folded away:
//  - softmax_k zeroes the LL-tag regions (18432B as dwords spread over its
//    32768 threads; plain stores, visible to later kernels via kernel-boundary
//    coherence -- the same proven mechanism that carries buildK's v=1.0 plain
//    stores into the loop kernel's sc0sc1 LLC reads).
//  - hipMemsetAsync removed: 4 dispatches -> 3.
//  Everything else is byte-for-byte round 8 (which passed, absmax 0.0).

static constexpr int N = 1024;
static constexpr int C = 64;

// Workspace layout (floats).
static constexpr int WS_XS  = 0;          // softmax(y_s[7]/2) : 1024*64
static constexpr int WS_YS  = 65536;      // softmax(y_t[7]/2) : 1024*64
static constexpr int WS_K   = 131072;     // K   : 1024*1024
static constexpr int WS_KT  = 1179648;    // K^T : 1024*1024
static constexpr int WS_ULL = 2228224;    // u LL units: 1024 x {f32,tag} = 2048 f
static constexpr int WS_VLL = 2230272;    // v LL units: 2048 f
static constexpr int WS_PLL = 2232320;    // partial LL units: 256 x {f32,tag}
static constexpr int LL_DWORDS = 2048 + 2048 + 512;   // 4608 dwords to zero

typedef float    f32x4 __attribute__((ext_vector_type(4)));
typedef unsigned u32x4 __attribute__((ext_vector_type(4)));
typedef unsigned u32x2 __attribute__((ext_vector_type(2)));

__device__ __forceinline__ float wsum(float v) {
    #pragma unroll
    for (int o = 32; o > 0; o >>= 1) v += __shfl_down(v, o, 64);
    return v;
}
__device__ __forceinline__ float wmax(float v) {
    #pragma unroll
    for (int o = 32; o > 0; o >>= 1) v = fmaxf(v, __shfl_down(v, o, 64));
    return v;
}

// Publish one LL unit {val, g}: single 8B store, sc0 sc1 -> lands at the LLC.
__device__ __forceinline__ void ll_write(float* unit, float val, unsigned g) {
    u32x2 d;
    d.x = __float_as_uint(val);
    d.y = g;
    asm volatile("global_store_dwordx2 %0, %1, off sc0 sc1"
                 :: "v"(unit), "v"(d) : "memory");
}

// Poll-read 4 LL units (thread t covers units t*4..t*4+3) into sv[t*4..].
// Two 16B sc0 sc1 loads per try; accept when all 4 embedded tags == g.
// 8B-atomic stores guarantee each {val,tag} pair is internally consistent.
__device__ __forceinline__ void ll_read4(const float* buf, unsigned g,
                                         float* sv, int t) {
    const float* p = buf + t * 8;          // 4 units * 2 floats
    u32x4 a, b;
    for (;;) {
        asm volatile(
            "global_load_dwordx4 %0, %2, off sc0 sc1\n\t"
            "global_load_dwordx4 %1, %2, off offset:16 sc0 sc1\n\t"
            "s_waitcnt vmcnt(0)"
            : "=&v"(a), "=&v"(b) : "v"(p) : "memory");
        if (a.y == g && a.w == g && b.y == g && b.w == g) break;
        __builtin_amdgcn_s_sleep(1);
    }
    const int u0 = t * 4;
    sv[u0 + 0] = __uint_as_float(a.x);
    sv[u0 + 1] = __uint_as_float(a.z);
    sv[u0 + 2] = __uint_as_float(b.x);
    sv[u0 + 3] = __uint_as_float(b.z);
}

// ---- 1: softmax over N axis (dim=1), batch 7. One block per column; 128
//         blocks. Also zeroes the LL regions (replaces the memset dispatch).
__global__ void __launch_bounds__(256)
softmax_k(const float* __restrict__ ysrc, const float* __restrict__ ytrc,
          float* __restrict__ ws)
{
    __shared__ float sm[4];
    const int tid = threadIdx.x, bid = blockIdx.x;
    const int wid = tid >> 6, lane = tid & 63;

    // Zero LL tag/value regions: 4608 dwords over the first 18 blocks.
    const int gidx = bid * 256 + tid;
    if (gidx < LL_DWORDS) ((unsigned*)(ws + WS_ULL))[gidx] = 0u;

    const float* src = ((bid < C) ? ysrc : ytrc) + 7 * N * C;
    float* dst = ws + ((bid < C) ? WS_XS : WS_YS);
    const int c = bid & (C - 1);

    float vals[4];
    float m = -1e30f;
    #pragma unroll
    for (int q = 0; q < 4; ++q) {
        vals[q] = src[(q * 256 + tid) * C + c] * 0.5f;   // y / T, T = 2
        m = fmaxf(m, vals[q]);
    }
    m = wmax(m);
    if (lane == 0) sm[wid] = m;
    __syncthreads();
    m = fmaxf(fmaxf(sm[0], sm[1]), fmaxf(sm[2], sm[3]));
    float s = 0.f;
    #pragma unroll
    for (int q = 0; q < 4; ++q) { vals[q] = expf(vals[q] - m); s += vals[q]; }
    s = wsum(s);
    __syncthreads();                 // protect sm reuse
    if (lane == 0) sm[wid] = s;
    __syncthreads();
    s = sm[0] + sm[1] + sm[2] + sm[3];
    const float inv = 1.0f / s;
    #pragma unroll
    for (int q = 0; q < 4; ++q) dst[(q * 256 + tid) * C + c] = vals[q] * inv;
}

// ---- 2: K_ij = exp(-10 * sum_c |x_ic - y_jc|), plus K^T; 32x32 tiles, 4/block.
//        Vectorized (round-7 proven): f32x4 staging; sy row register-blocked
//        (one load serves all 4 q-outputs); sx f32x4 broadcast reads.
//        Accumulation order exactly the scalar original (c ascending, single
//        accumulator) -> bitwise-identical K.
//        Blocks 0..3 write the initial v LL units' VALUE slots (1.0f); tags
//        stay 0 from softmax_k's zeroing (= expected tag of generation 0).
__global__ void __launch_bounds__(256)
buildK_k(float* __restrict__ ws)
{
    __shared__ __align__(16) float sx[32 * 64];
    __shared__ __align__(16) float sy[32 * 68];   // stride 68: 16B-aligned rows
    __shared__ float kt[32 * 33];
    float* xs  = ws + WS_XS;
    float* ysm = ws + WS_YS;
    float* K   = ws + WS_K;
    float* KT  = ws + WS_KT;
    const int tid = threadIdx.x, bid = blockIdx.x;
    const int jl = tid & 31;

    if (bid < 4) ws[WS_VLL + (bid * 256 + tid) * 2] = 1.0f;   // v := 1 (LL value)

    #pragma unroll 1
    for (int t = 0; t < 4; ++t) {
        const int tt = bid * 4 + t;
        const int ti = tt >> 5, tj = tt & 31;
        __syncthreads();
        {   // stage x tile (stride 64) and y tile (stride 68), f32x4
            const f32x4* xsrc = (const f32x4*)(xs + ti * 2048);
            f32x4* dx = (f32x4*)sx;
            dx[tid]       = xsrc[tid];
            dx[tid + 256] = xsrc[tid + 256];
            const f32x4* ysrc = (const f32x4*)(ysm + tj * 2048);
            #pragma unroll
            for (int h = 0; h < 2; ++h) {
                const int k4 = tid + h * 256;          // f32x4 index 0..511
                const int row = k4 >> 4, c4 = k4 & 15;
                *(f32x4*)&sy[row * 68 + c4 * 4] = ysrc[k4];
            }
        }
        __syncthreads();
        // Register-load this thread's sy row (shared by all 4 q-outputs).
        f32x4 yr[16];
        #pragma unroll
        for (int c4 = 0; c4 < 16; ++c4)
            yr[c4] = *(const f32x4*)&sy[jl * 68 + c4 * 4];
        float kv[4];
        #pragma unroll
        for (int q = 0; q < 4; ++q) {
            const int il = (q * 256 + tid) >> 5;
            float a = 0.f;
            #pragma unroll
            for (int c4 = 0; c4 < 16; ++c4) {
                const f32x4 xv = *(const f32x4*)&sx[il * 64 + c4 * 4];
                a += fabsf(xv.x - yr[c4].x);        // c = 4*c4 + 0..3,
                a += fabsf(xv.y - yr[c4].y);        // ascending, single acc:
                a += fabsf(xv.z - yr[c4].z);        // identical order to the
                a += fabsf(xv.w - yr[c4].w);        // scalar original
            }
            kv[q] = expf(-10.0f * a);                       // exp(-W/eps)
            K[(ti * 32 + il) * N + tj * 32 + jl] = kv[q];   // coalesced over jl
        }
        __syncthreads();
        #pragma unroll
        for (int q = 0; q < 4; ++q) {
            const int idx = q * 256 + tid;
            kt[(idx >> 5) * 33 + (idx & 31)] = kv[q];
        }
        __syncthreads();
        #pragma unroll
        for (int q = 0; q < 4; ++q) {
            const int idx = q * 256 + tid;
            const int jl2 = idx >> 5, il2 = idx & 31;
            KT[(tj * 32 + jl2) * N + ti * 32 + il2] = kt[il2 * 33 + jl2];
        }
    }
}

// ---- 3: persistent loop kernel (round-6/8 EXACT). 64 blocks x 256 threads;
//         block owns rows bid*16..bid*16+15 of K and KT, resident in LDS.
//         Cross-block exchange via LL units; BATCHED publish: each block's 16
//         units = one 128B line, written in one shot by threads 0..15.
__global__ void __launch_bounds__(256)
sinkhorn_loop_k(float* __restrict__ ws, float* __restrict__ out)
{
    __shared__ __align__(16) float rows[32 * 1024];  // K rows | KT rows (128KB)
    __shared__ __align__(16) float sv[1024];
    __shared__ float stage[16];
    __shared__ float fsm[4];
    const int tid = threadIdx.x, bid = blockIdx.x;
    const int wid = tid >> 6, lane = tid & 63;

    // Preload this block's 16 K rows + 16 KT rows (rows are contiguous).
    {
        const f32x4* Ksrc  = (const f32x4*)(ws + WS_K  + bid * 16 * N);
        const f32x4* KTsrc = (const f32x4*)(ws + WS_KT + bid * 16 * N);
        f32x4* dK  = (f32x4*)rows;
        f32x4* dKT = (f32x4*)(rows + 16 * N);
        #pragma unroll 4
        for (int q = 0; q < 16; ++q) dK[tid + 256 * q]  = Ksrc[tid + 256 * q];
        #pragma unroll 4
        for (int q = 0; q < 16; ++q) dKT[tid + 256 * q] = KTsrc[tid + 256 * q];
    }
    __syncthreads();

    float* uLL = ws + WS_ULL;
    float* vLL = ws + WS_VLL;
    float* pLL = ws + WS_PLL;
    const float* rK  = rows + (wid * 4) * N;
    const float* rKT = rows + 16 * N + (wid * 4) * N;
    float u_s[4];
    unsigned g = 0;          // generation: u-steps publish odd, v-steps even

    #pragma unroll 1
    for (int it = 0; it < 20; ++it) {
        // ---- u = 1/(K v): consume v@g, publish u@g+1.
        ll_read4(vLL, g, sv, tid);
        __syncthreads();
        #pragma unroll
        for (int s = 0; s < 4; ++s) {
            const f32x4* Kr = (const f32x4*)(rK + s * N);
            const f32x4 k0 = Kr[lane], k1 = Kr[lane + 64],
                        k2 = Kr[lane + 128], k3 = Kr[lane + 192];
            const f32x4 b0 = *(const f32x4*)&sv[(lane) * 4];
            const f32x4 b1 = *(const f32x4*)&sv[(lane + 64) * 4];
            const f32x4 b2 = *(const f32x4*)&sv[(lane + 128) * 4];
            const f32x4 b3 = *(const f32x4*)&sv[(lane + 192) * 4];
            float acc = 0.f;
            acc += k0.x * b0.x + k0.y * b0.y + k0.z * b0.z + k0.w * b0.w;
            acc += k1.x * b1.x + k1.y * b1.y + k1.z * b1.z + k1.w * b1.w;
            acc += k2.x * b2.x + k2.y * b2.y + k2.z * b2.z + k2.w * b2.w;
            acc += k3.x * b3.x + k3.y * b3.y + k3.z * b3.z + k3.w * b3.w;
            acc = wsum(acc);
            if (lane == 0) { u_s[s] = 1.0f / acc; stage[wid * 4 + s] = u_s[s]; }
        }
        __syncthreads();     // all dots done (sv free), stage complete
        ++g;
        if (tid < 16) ll_write(uLL + (bid * 16 + tid) * 2, stage[tid], g);

        // ---- v = 1/(K^T u): consume u@g, publish v@g+1.
        ll_read4(uLL, g, sv, tid);
        __syncthreads();
        #pragma unroll
        for (int s = 0; s < 4; ++s) {
            const f32x4* Kr = (const f32x4*)(rKT + s * N);
            const f32x4 k0 = Kr[lane], k1 = Kr[lane + 64],
                        k2 = Kr[lane + 128], k3 = Kr[lane + 192];
            const f32x4 b0 = *(const f32x4*)&sv[(lane) * 4];
            const f32x4 b1 = *(const f32x4*)&sv[(lane + 64) * 4];
            const f32x4 b2 = *(const f32x4*)&sv[(lane + 128) * 4];
            const f32x4 b3 = *(const f32x4*)&sv[(lane + 192) * 4];
            float acc = 0.f;
            acc += k0.x * b0.x + k0.y * b0.y + k0.z * b0.z + k0.w * b0.w;
            acc += k1.x * b1.x + k1.y * b1.y + k1.z * b1.z + k1.w * b1.w;
            acc += k2.x * b2.x + k2.y * b2.y + k2.z * b2.z + k2.w * b2.w;
            acc += k3.x * b3.x + k3.y * b3.y + k3.z * b3.z + k3.w * b3.w;
            acc = wsum(acc);
            if (lane == 0) stage[wid * 4 + s] = 1.0f / acc;
        }
        __syncthreads();
        ++g;
        if (tid < 16) ll_write(vLL + (bid * 16 + tid) * 2, stage[tid], g);
    }

    // ---- Loss: consume final v@40; partials as LL units tagged 41.
    ll_read4(vLL, g, sv, tid);           // g == 40
    __syncthreads();
    {
        float p = 0.f;
        #pragma unroll
        for (int s = 0; s < 4; ++s) {
            const float* Kr = rK + s * N;      // LDS copy == K row bits
            float acc = 0.f;
            for (int j = lane; j < N; j += 64) {
                const float kk = Kr[j];
                acc += kk * sv[j] * logf(kk);
            }
            acc = wsum(acc);
            if (lane == 0) p += u_s[s] * acc;
        }
        if (lane == 0) ll_write(pLL + (bid * 4 + wid) * 2, p, 41u);
    }

    // ---- final: block 0 polls the 256 partial units, reduces, writes out.
    if (bid == 0) {
        const float* pp = pLL + tid * 2;
        u32x2 c;
        for (;;) {
            asm volatile("global_load_dwordx2 %0, %1, off sc0 sc1\n\t"
                         "s_waitcnt vmcnt(0)"
                         : "=&v"(c) : "v"(pp) : "memory");
            if (c.y == 41u) break;
            __builtin_amdgcn_s_sleep(1);
        }
        float acc = __uint_as_float(c.x);
        acc = wsum(acc);
        if (lane == 0) fsm[wid] = acc;
        __syncthreads();
        if (tid == 0)
            out[0] = -1e-4f * (fsm[0] + fsm[1] + fsm[2] + fsm[3]);  // 1e-3*(-0.1)
    }
}

extern "C" void kernel_launch(void* const* d_in, const int* in_sizes, int n_in,
                              void* d_out, int out_size, void* d_ws, size_t ws_size,
                              hipStream_t stream) {
    const float* y_s = (const float*)d_in[0];
    const float* y_t = (const float*)d_in[1];
    float* ws = (float*)d_ws;

    softmax_k<<<dim3(128), dim3(256), 0, stream>>>(y_s, y_t, ws);
    buildK_k<<<dim3(256), dim3(256), 0, stream>>>(ws);
    sinkhorn_loop_k<<<dim3(64), dim3(256), 0, stream>>>(ws, (float*)d_out);
}